// Round 1
// baseline (317.527 us; speedup 1.0000x reference)
//
#include <hip/hip_runtime.h>

#define MAXT 10000
#define BATCH 4096
#define NT_SETUP 512
#define SEG 20            // 512*20 = 10240 >= MAXT
#define TCHUNK 16
#define CUT_LOGIT -27.7f  // max gumbel noise is -log(1e-12) = 27.6310; below this no gate fires

// ---------------- block-wide exclusive scan (512 threads) ----------------
// Exclusive value taken from neighbor's inclusive sum (NOT incl - v) so that
// -inf segments don't produce NaN.
__device__ __forceinline__ float block_exscan(float v, float* sh, int tid) {
    sh[tid] = v;
    __syncthreads();
    for (int off = 1; off < NT_SETUP; off <<= 1) {
        float x = (tid >= off) ? sh[tid - off] : 0.0f;
        __syncthreads();
        sh[tid] += x;
        __syncthreads();
    }
    float excl = (tid > 0) ? sh[tid - 1] : 0.0f;
    __syncthreads();   // sh reusable after return
    return excl;
}

__global__ __launch_bounds__(NT_SETUP) void setup_kernel(
    const float* __restrict__ acts,
    float* __restrict__ logit,    // [MAXT]
    float* __restrict__ rpref,    // [MAXT+1] exclusive prefix of r_t, [MAXT]=total
    float* __restrict__ cbuf,     // [MAXT] scratch: logp increments
    int*   __restrict__ tcut,
    int*   __restrict__ firstfire)
{
    __shared__ float sh[NT_SETUP];
    __shared__ int   shi[NT_SETUP];
    const int tid = threadIdx.x;

    const float LOG_GAMMA = 1.9802627296e-2f;   // log(1.02)
    const float ALPHA     = -1.0050335854e-5f;  // log(0.99)/1000
    const float INIT_LOGW = -1.3943265329f;     // log(0.248)
    const float INIT_LOGP = -6.9077552790f;     // log(0.001)

    // init per-batch first-fire table (ws is poisoned before every call)
    for (int i = tid; i < BATCH; i += NT_SETUP) firstfire[i] = MAXT;

    const int t0 = tid * SEG;
    const int n  = (t0 < MAXT) ? min(SEG, MAXT - t0) : 0;

    // ---- pass A: logw (prefix of d_t), emit c_t and r_t ----
    float lsum = 0.0f;
    for (int i = 0; i < n; ++i) {
        float f = expf(acts[t0 + i]);
        lsum += LOG_GAMMA + logf(1.0f - f);
    }
    float excl = block_exscan(lsum, sh, tid);
    float run = INIT_LOGW + excl;          // logw BEFORE step t
    for (int i = 0; i < n; ++i) {
        int t = t0 + i;
        float f = expf(acts[t]);
        float d = LOG_GAMMA + logf(1.0f - f);
        cbuf[t]  = ALPHA * f * expf(run);              // uses OLD logw (ref semantics)
        rpref[t] = expf((run + d) * (1.0f / 1000.0f)); // r_t from NEW logw
        run += d;
    }
    // threads only touch their own segment of cbuf/rpref -> no sync needed

    // ---- pass B: logp prefix -> logit, find Tcut ----
    float csum = 0.0f;
    for (int i = 0; i < n; ++i) csum += cbuf[t0 + i];
    excl = block_exscan(csum, sh, tid);
    float logp = INIT_LOGP + excl;         // logp BEFORE step t
    int localFirst = MAXT;
    for (int i = 0; i < n; ++i) {
        int t = t0 + i;
        float lg = logp - log1pf(-expf(logp));  // -inf handled: exp(-inf)=0 -> lg=-inf
        logit[t] = lg;
        if (localFirst == MAXT && lg <= CUT_LOGIT) localFirst = t;
        logp += cbuf[t];
    }
    shi[tid] = localFirst;
    __syncthreads();
    for (int off = NT_SETUP / 2; off > 0; off >>= 1) {
        if (tid < off) shi[tid] = min(shi[tid], shi[tid + off]);
        __syncthreads();
    }
    if (tid == 0) tcut[0] = shi[0];

    // ---- pass C: exclusive prefix of r_t (in place) ----
    float rsum = 0.0f;
    for (int i = 0; i < n; ++i) rsum += rpref[t0 + i];
    excl = block_exscan(rsum, sh, tid);
    float rrun = excl;
    for (int i = 0; i < n; ++i) {
        int t = t0 + i;
        float v = rpref[t];
        rpref[t] = rrun;
        rrun += v;
    }
    if (n > 0 && (t0 + n) == MAXT) rpref[MAXT] = rrun;  // grand total
}

// ---------------- main gate scan: find first firing step per batch elem ----
__global__ __launch_bounds__(256) void scan_kernel(
    const float* __restrict__ u1, const float* __restrict__ u2,
    const float* __restrict__ logit, const int* __restrict__ tcutp,
    int* __restrict__ firstfire)
{
    __shared__ int   s_tcut;
    __shared__ float s_logit[TCHUNK];
    const int tid = threadIdx.x;
    if (tid == 0) s_tcut = *tcutp;
    __syncthreads();
    const int tcut = s_tcut;
    const int tstart = blockIdx.y * TCHUNK;
    if (tstart >= tcut) return;   // beyond cutoff: no gate can fire
    const int tend = min(tstart + TCHUNK, tcut);
    if (tid < tend - tstart) s_logit[tid] = logit[tstart + tid];
    __syncthreads();

    const int b = blockIdx.x * 256 + tid;
    const float EPSF = 1e-12f;
    int found = MAXT;
    for (int t = tstart; t < tend; ++t) {
        float a = u1[(size_t)t * BATCH + b];
        float c = u2[(size_t)t * BATCH + b];
        float noise = -logf(logf(c + EPSF) / logf(a + EPSF) + EPSF);
        if (s_logit[t - tstart] + noise > 0.0f) { found = t; break; }
    }
    if (found != MAXT) atomicMin(firstfire + b, found);
}

// ---------------- finalize: cumrew[b] = Rprefix[T_b]; mean over batch ------
__global__ __launch_bounds__(1024) void finalize_kernel(
    const int* __restrict__ firstfire, const float* __restrict__ rpref,
    float* __restrict__ out)
{
    __shared__ double ssum[1024];
    const int tid = threadIdx.x;
    double s = 0.0;
    for (int i = tid; i < BATCH; i += 1024) {
        int t = firstfire[i];          // == MAXT if never fired -> rpref[MAXT] = total
        s += (double)rpref[t];
    }
    ssum[tid] = s;
    __syncthreads();
    for (int off = 512; off > 0; off >>= 1) {
        if (tid < off) ssum[tid] += ssum[tid + off];
        __syncthreads();
    }
    if (tid == 0) out[0] = (float)(ssum[0] / (double)BATCH);
}

extern "C" void kernel_launch(void* const* d_in, const int* in_sizes, int n_in,
                              void* d_out, int out_size, void* d_ws, size_t ws_size,
                              hipStream_t stream) {
    const float* acts = (const float*)d_in[0];
    const float* u1   = (const float*)d_in[1];
    const float* u2   = (const float*)d_in[2];
    float* out = (float*)d_out;

    float* W       = (float*)d_ws;
    float* logit   = W;                       // MAXT floats
    float* rpref   = W + MAXT;                // MAXT+1 floats
    float* cbuf    = W + 2 * MAXT + 4;        // MAXT floats (16B-aligned offset)
    int*   tcut    = (int*)(W + 3 * MAXT + 8);
    int*   ffire   = tcut + 4;                // BATCH ints

    setup_kernel<<<1, NT_SETUP, 0, stream>>>(acts, logit, rpref, cbuf, tcut, ffire);

    dim3 grid(BATCH / 256, (MAXT + TCHUNK - 1) / TCHUNK);
    scan_kernel<<<grid, 256, 0, stream>>>(u1, u2, logit, tcut, ffire);

    finalize_kernel<<<1, 1024, 0, stream>>>(ffire, rpref, out);
}

// Round 2
// 315.272 us; speedup vs baseline: 1.0071x; 1.0071x over previous
//
#include <hip/hip_runtime.h>

#define MAXT 10000
#define BATCH 4096
#define NT_SETUP 512
#define SEG 20            // 512*20 = 10240 >= MAXT
#define TCHUNK 16
#define NYB 80            // t-chunk blocks in grid.y (grid-stride covers any tcut)
#define CUT_LOGIT -27.7f  // max gumbel noise is -log(1e-12) = 27.6310; below this no gate fires

// ---------------- block-wide exclusive scan (512 threads) ----------------
// Exclusive value taken from neighbor's inclusive sum (NOT incl - v) so that
// -inf segments don't produce NaN.
__device__ __forceinline__ float block_exscan(float v, float* sh, int tid) {
    sh[tid] = v;
    __syncthreads();
    for (int off = 1; off < NT_SETUP; off <<= 1) {
        float x = (tid >= off) ? sh[tid - off] : 0.0f;
        __syncthreads();
        sh[tid] += x;
        __syncthreads();
    }
    float excl = (tid > 0) ? sh[tid - 1] : 0.0f;
    __syncthreads();   // sh reusable after return
    return excl;
}

__global__ __launch_bounds__(NT_SETUP) void setup_kernel(
    const float* __restrict__ acts,
    float* __restrict__ gate,     // [MAXT]  c_t = exp(logit_t) - EPS
    float* __restrict__ rpref,    // [MAXT+1] exclusive prefix of r_t, [MAXT]=total
    float* __restrict__ cbuf,     // [MAXT] scratch: logp increments
    int*   __restrict__ tcut,
    int*   __restrict__ firstfire)
{
    __shared__ float sh[NT_SETUP];
    __shared__ int   shi[NT_SETUP];
    const int tid = threadIdx.x;

    const float LOG_GAMMA = 1.9802627296e-2f;   // log(1.02)
    const float ALPHA     = -1.0050335854e-5f;  // log(0.99)/1000
    const float INIT_LOGW = -1.3943265329f;     // log(0.248)
    const float INIT_LOGP = -6.9077552790f;     // log(0.001)

    // init per-batch first-fire table (ws is poisoned before every call)
    for (int i = tid; i < BATCH; i += NT_SETUP) firstfire[i] = MAXT;

    const int t0 = tid * SEG;
    const int n  = (t0 < MAXT) ? min(SEG, MAXT - t0) : 0;

    // ---- pass A: logw (prefix of d_t), emit c_t (logp increments) and r_t ----
    float lsum = 0.0f;
    for (int i = 0; i < n; ++i) {
        float f = expf(acts[t0 + i]);
        lsum += LOG_GAMMA + logf(1.0f - f);
    }
    float excl = block_exscan(lsum, sh, tid);
    float run = INIT_LOGW + excl;          // logw BEFORE step t
    for (int i = 0; i < n; ++i) {
        int t = t0 + i;
        float f = expf(acts[t]);
        float d = LOG_GAMMA + logf(1.0f - f);
        cbuf[t]  = ALPHA * f * expf(run);              // uses OLD logw (ref semantics)
        rpref[t] = expf((run + d) * (1.0f / 1000.0f)); // r_t from NEW logw
        run += d;
    }
    // threads only touch their own segment of cbuf/rpref -> no sync needed

    // ---- pass B: logp prefix -> gate threshold, find Tcut ----
    float csum = 0.0f;
    for (int i = 0; i < n; ++i) csum += cbuf[t0 + i];
    excl = block_exscan(csum, sh, tid);
    float logp = INIT_LOGP + excl;         // logp BEFORE step t
    int localFirst = MAXT;
    for (int i = 0; i < n; ++i) {
        int t = t0 + i;
        float lg = logp - log1pf(-expf(logp));  // -inf handled: exp(-inf)=0 -> lg=-inf
        // fire iff  log(u2+E)/log(u1+E) + E < exp(lg)  <=>  L2 > c*L1 (L1<0)
        gate[t] = expf(lg) - 1e-12f;            // lg=-inf -> c=-1e-12 -> never fires
        if (localFirst == MAXT && lg <= CUT_LOGIT) localFirst = t;
        logp += cbuf[t];
    }
    shi[tid] = localFirst;
    __syncthreads();
    for (int off = NT_SETUP / 2; off > 0; off >>= 1) {
        if (tid < off) shi[tid] = min(shi[tid], shi[tid + off]);
        __syncthreads();
    }
    if (tid == 0) tcut[0] = shi[0];

    // ---- pass C: exclusive prefix of r_t (in place) ----
    float rsum = 0.0f;
    for (int i = 0; i < n; ++i) rsum += rpref[t0 + i];
    excl = block_exscan(rsum, sh, tid);
    float rrun = excl;
    for (int i = 0; i < n; ++i) {
        int t = t0 + i;
        float v = rpref[t];
        rpref[t] = rrun;
        rrun += v;
    }
    if (n > 0 && (t0 + n) == MAXT) rpref[MAXT] = rrun;  // grand total
}

// ---------------- main gate scan: find first firing step per batch elem ----
// One lane owns 4 consecutive batch elems (float4 loads, 16 B/lane).
// No early break: fires are rare and all of u1/u2 below tcut must be read
// anyway, so we pipeline all loads (4 t-steps' loads in flight per group).
__global__ __launch_bounds__(256) void scan_kernel(
    const float* __restrict__ u1, const float* __restrict__ u2,
    const float* __restrict__ gate, const int* __restrict__ tcutp,
    int* __restrict__ firstfire)
{
    const int tid = threadIdx.x;
    const int b4  = (blockIdx.x * 256 + tid) * 4;
    const int tcut = *tcutp;               // wave-uniform scalar load
    const float E = 1e-12f;

    int f0 = MAXT, f1 = MAXT, f2 = MAXT, f3 = MAXT;

    for (int chunk = blockIdx.y; chunk * TCHUNK < tcut; chunk += gridDim.y) {
        const int tbase = chunk * TCHUNK;
        // full fixed-trip chunk: steps >= tcut inside the chunk use their real
        // gate values (they cannot fire mathematically), keeps loop unrollable
        #pragma unroll
        for (int g = 0; g < TCHUNK / 4; ++g) {
            float4 a[4], c[4];
            float gv[4];
            #pragma unroll
            for (int j = 0; j < 4; ++j) {
                const int t = tbase + g * 4 + j;
                a[j]  = *(const float4*)(u1 + (size_t)t * BATCH + b4);
                c[j]  = *(const float4*)(u2 + (size_t)t * BATCH + b4);
                gv[j] = gate[t];
            }
            #pragma unroll
            for (int j = 0; j < 4; ++j) {
                const int t = tbase + g * 4 + j;
                const float k = gv[j];
                if (__logf(c[j].x + E) > k * __logf(a[j].x + E)) f0 = min(f0, t);
                if (__logf(c[j].y + E) > k * __logf(a[j].y + E)) f1 = min(f1, t);
                if (__logf(c[j].z + E) > k * __logf(a[j].z + E)) f2 = min(f2, t);
                if (__logf(c[j].w + E) > k * __logf(a[j].w + E)) f3 = min(f3, t);
            }
        }
    }

    if (f0 != MAXT) atomicMin(firstfire + b4 + 0, f0);
    if (f1 != MAXT) atomicMin(firstfire + b4 + 1, f1);
    if (f2 != MAXT) atomicMin(firstfire + b4 + 2, f2);
    if (f3 != MAXT) atomicMin(firstfire + b4 + 3, f3);
}

// ---------------- finalize: cumrew[b] = Rprefix[T_b]; mean over batch ------
__global__ __launch_bounds__(1024) void finalize_kernel(
    const int* __restrict__ firstfire, const float* __restrict__ rpref,
    float* __restrict__ out)
{
    __shared__ double ssum[1024];
    const int tid = threadIdx.x;
    double s = 0.0;
    for (int i = tid; i < BATCH; i += 1024) {
        int t = firstfire[i];          // == MAXT if never fired -> rpref[MAXT] = total
        s += (double)rpref[t];
    }
    ssum[tid] = s;
    __syncthreads();
    for (int off = 512; off > 0; off >>= 1) {
        if (tid < off) ssum[tid] += ssum[tid + off];
        __syncthreads();
    }
    if (tid == 0) out[0] = (float)(ssum[0] / (double)BATCH);
}

extern "C" void kernel_launch(void* const* d_in, const int* in_sizes, int n_in,
                              void* d_out, int out_size, void* d_ws, size_t ws_size,
                              hipStream_t stream) {
    const float* acts = (const float*)d_in[0];
    const float* u1   = (const float*)d_in[1];
    const float* u2   = (const float*)d_in[2];
    float* out = (float*)d_out;

    float* W       = (float*)d_ws;
    float* gate    = W;                       // MAXT floats
    float* rpref   = W + MAXT;                // MAXT+1 floats
    float* cbuf    = W + 2 * MAXT + 4;        // MAXT floats (16B-aligned offset)
    int*   tcut    = (int*)(W + 3 * MAXT + 8);
    int*   ffire   = tcut + 4;                // BATCH ints

    setup_kernel<<<1, NT_SETUP, 0, stream>>>(acts, gate, rpref, cbuf, tcut, ffire);

    dim3 grid(BATCH / (256 * 4), NYB);        // (4, 80) = 320 blocks
    scan_kernel<<<grid, 256, 0, stream>>>(u1, u2, gate, tcut, ffire);

    finalize_kernel<<<1, 1024, 0, stream>>>(ffire, rpref, out);
}

// Round 3
// 291.387 us; speedup vs baseline: 1.0897x; 1.0820x over previous
//
#include <hip/hip_runtime.h>
#include <limits.h>

#define MAXT 10000
#define BATCH 4096
#define NYB 80            // slot rows / y-blocks
#define TCHUNK 16
#define SEGT 1536         // t-steps per prefix segment in scan kernel (256*6)
#define EPT 6             // prefix elems per thread in scan kernel
#define NT2 1024
#define SEG2 10           // 1024*10 = 10240 >= MAXT
#define CUT_ODDS 9.3e-13f // odds <= this  <=>  logit <= -27.70 < -(-log(1e-12)) => no fire possible

#define LOG_GAMMA_C  1.9802627296e-2f   // log(1.02)
#define ALPHA_C     -1.0050335854e-5f   // log(0.99)/1000
#define INIT_LOGW_C -1.3943265329f      // log(0.248)
#define INIT_LOGP_C -6.9077552790f      // log(0.001)
#define EPS_C        1e-12f

// Block-wide exclusive scan + total. Exclusive value taken from the
// neighbor's inclusive sum (NOT incl - v) so -inf segments don't make NaN.
__device__ __forceinline__ float block_exscan_tot(float v, float* sh, int tid,
                                                  int n, float* tot) {
    sh[tid] = v;
    __syncthreads();
    for (int off = 1; off < n; off <<= 1) {
        float x = (tid >= off) ? sh[tid - off] : 0.0f;
        __syncthreads();
        sh[tid] += x;
        __syncthreads();
    }
    float excl = (tid > 0) ? sh[tid - 1] : 0.0f;
    float t_ = sh[n - 1];
    __syncthreads();   // sh reusable after return
    *tot = t_;
    return excl;
}

// ---- fused gate-prefix + first-fire scan ---------------------------------
// Every block recomputes the (cheap, t-only) gate sequence itself in LDS,
// then scans its share of u1/u2 chunks. No cross-block dependencies; each
// block writes its min-fire table row unconditionally (no init, no atomics).
__global__ __launch_bounds__(256) void scan_fused(
    const float* __restrict__ acts,
    const float* __restrict__ u1, const float* __restrict__ u2,
    unsigned* __restrict__ fftab)   // [NYB][BATCH]
{
    __shared__ float sh[256];
    __shared__ int   shi[256];
    __shared__ float s_gate[SEGT];

    const int tid = threadIdx.x;
    const int b4  = (blockIdx.x * 256 + tid) * 4;
    const float E = EPS_C;

    float carry_w = INIT_LOGW_C;
    float carry_p = INIT_LOGP_C;
    unsigned f0 = MAXT, f1 = MAXT, f2 = MAXT, f3 = MAXT;

    for (int seg_base = 0; seg_base < MAXT; seg_base += SEGT) {
        // ---- gate prefix for t in [seg_base, seg_base+SEGT) ----
        float fv[EPT], dv[EPT];
        float lsum = 0.0f;
        #pragma unroll
        for (int i = 0; i < EPT; ++i) {
            int t = seg_base + tid * EPT + i;
            if (t < MAXT) {
                float f = expf(acts[t]);
                fv[i] = f;
                dv[i] = LOG_GAMMA_C + logf(1.0f - f);
            } else { fv[i] = 0.0f; dv[i] = 0.0f; }
            lsum += dv[i];
        }
        float dtot;
        float excl = block_exscan_tot(lsum, sh, tid, 256, &dtot);

        float run = carry_w + excl;        // logw BEFORE step t
        float cv[EPT];
        float csum = 0.0f;
        #pragma unroll
        for (int i = 0; i < EPT; ++i) {
            cv[i] = ALPHA_C * fv[i] * expf(run);   // uses OLD logw (ref semantics)
            run += dv[i];
            csum += cv[i];
        }
        float ctot;
        float cexcl = block_exscan_tot(csum, sh, tid, 256, &ctot);

        float logp = carry_p + cexcl;      // logp BEFORE step t
        int localFirst = INT_MAX;
        #pragma unroll
        for (int i = 0; i < EPT; ++i) {
            int t = seg_base + tid * EPT + i;
            float el   = expf(logp);               // -inf -> 0
            float odds = el / (1.0f - el);         // = exp(logit)
            s_gate[tid * EPT + i] = odds - E;      // fire iff R < gate
            if (localFirst == INT_MAX && odds <= CUT_ODDS) localFirst = t;
            logp += cv[i];
        }
        shi[tid] = localFirst;
        __syncthreads();                   // also covers s_gate writes
        for (int off = 128; off > 0; off >>= 1) {
            if (tid < off) shi[tid] = min(shi[tid], shi[tid + off]);
            __syncthreads();
        }
        const int segcut = shi[0];         // uniform; INT_MAX if none
        __syncthreads();                   // shi reusable next segment

        // ---- scan this block's chunks within the segment ----
        const int tlimit = min(segcut, MAXT);   // process chunks with tstart < tlimit
        for (int lc = 0; lc < SEGT / TCHUNK; ++lc) {
            const int cg = seg_base / TCHUNK + lc;
            if ((cg % NYB) != (int)blockIdx.y) continue;
            const int tstart = seg_base + lc * TCHUNK;
            if (tstart >= tlimit) break;
            // fixed-trip 16 steps: steps past tlimit use real gate values
            // (cannot fire mathematically) -> fully unrollable, loads pipeline
            #pragma unroll
            for (int g = 0; g < TCHUNK / 4; ++g) {
                float4 a[4], c[4];
                float gv[4];
                #pragma unroll
                for (int j = 0; j < 4; ++j) {
                    const int t = tstart + g * 4 + j;
                    a[j]  = *(const float4*)(u1 + (size_t)t * BATCH + b4);
                    c[j]  = *(const float4*)(u2 + (size_t)t * BATCH + b4);
                    gv[j] = s_gate[t - seg_base];
                }
                #pragma unroll
                for (int j = 0; j < 4; ++j) {
                    const unsigned t = (unsigned)(tstart + g * 4 + j);
                    const float k = gv[j];
                    // fire iff log(u2+E)/log(u1+E) + E < exp(logit)
                    //      iff log(u2+E) > gate * log(u1+E)   (log(u1+E) < 0)
                    if (__logf(c[j].x + E) > k * __logf(a[j].x + E)) f0 = min(f0, t);
                    if (__logf(c[j].y + E) > k * __logf(a[j].y + E)) f1 = min(f1, t);
                    if (__logf(c[j].z + E) > k * __logf(a[j].z + E)) f2 = min(f2, t);
                    if (__logf(c[j].w + E) > k * __logf(a[j].w + E)) f3 = min(f3, t);
                }
            }
        }

        if (segcut != INT_MAX) break;      // uniform: no gate can fire beyond
        carry_w += dtot;
        carry_p += ctot;
        __syncthreads();                   // all chunk reads of s_gate done
    }

    // unconditional slot write: no init / no atomics needed
    uint4 outv; outv.x = f0; outv.y = f1; outv.z = f2; outv.w = f3;
    *(uint4*)(fftab + (size_t)blockIdx.y * BATCH + b4) = outv;
}

// ---- finalize: rpref prefix in LDS, min over slot rows, mean -------------
__global__ __launch_bounds__(NT2) void finalize_kernel(
    const float* __restrict__ acts,
    const unsigned* __restrict__ fftab,
    float* __restrict__ out)
{
    __shared__ float  sh[NT2];
    __shared__ float  rp[MAXT + 1];
    __shared__ double sd[NT2];
    const int tid = threadIdx.x;

    const int t0 = tid * SEG2;
    const int n  = (t0 < MAXT) ? min(SEG2, MAXT - t0) : 0;

    float dv[SEG2];
    float lsum = 0.0f;
    for (int i = 0; i < n; ++i) {
        float f = expf(acts[t0 + i]);
        dv[i] = LOG_GAMMA_C + logf(1.0f - f);
        lsum += dv[i];
    }
    float dtot;
    float excl = block_exscan_tot(lsum, sh, tid, NT2, &dtot);
    float run = INIT_LOGW_C + excl;        // logw BEFORE step t

    float rv[SEG2];
    float rsum = 0.0f;
    for (int i = 0; i < n; ++i) {
        run += dv[i];                      // logw AFTER step t
        rv[i] = expf(run * 1e-3f);         // r_t = exp(new_logw / 1000)
        rsum += rv[i];
    }
    float rtot;
    float rexcl = block_exscan_tot(rsum, sh, tid, NT2, &rtot);
    float rrun = rexcl;
    for (int i = 0; i < n; ++i) { rp[t0 + i] = rrun; rrun += rv[i]; }
    if (tid == 0) rp[MAXT] = rtot;         // never-fired -> full sum
    __syncthreads();

    double s = 0.0;
    for (int b = tid; b < BATCH; b += NT2) {
        unsigned ff = 0xFFFFFFFFu;
        #pragma unroll 8
        for (int y = 0; y < NYB; ++y) ff = min(ff, fftab[(size_t)y * BATCH + b]);
        int t = (int)min(ff, (unsigned)MAXT);
        s += (double)rp[t];
    }
    sd[tid] = s;
    __syncthreads();
    for (int off = NT2 / 2; off > 0; off >>= 1) {
        if (tid < off) sd[tid] += sd[tid + off];
        __syncthreads();
    }
    if (tid == 0) out[0] = (float)(sd[0] / (double)BATCH);
}

extern "C" void kernel_launch(void* const* d_in, const int* in_sizes, int n_in,
                              void* d_out, int out_size, void* d_ws, size_t ws_size,
                              hipStream_t stream) {
    const float* acts = (const float*)d_in[0];
    const float* u1   = (const float*)d_in[1];
    const float* u2   = (const float*)d_in[2];
    float* out = (float*)d_out;

    unsigned* fftab = (unsigned*)d_ws;     // NYB*BATCH uints = 1.3 MB

    dim3 grid(BATCH / (256 * 4), NYB);     // (4, 80) = 320 blocks
    scan_fused<<<grid, 256, 0, stream>>>(acts, u1, u2, fftab);
    finalize_kernel<<<1, NT2, 0, stream>>>(acts, fftab, out);
}